// Round 2
// 1013.439 us; speedup vs baseline: 1.1625x; 1.1625x over previous
//
#include <hip/hip_runtime.h>

#define BB 2048
#define TT 2048
#define HH 16

typedef __attribute__((ext_vector_type(2))) float f32x2;
typedef __attribute__((ext_vector_type(4))) float f32x4;

__device__ __forceinline__ float bperm(int byteaddr, float v) {
    return __int_as_float(__builtin_amdgcn_ds_bpermute(byteaddr, __float_as_int(v)));
}
__device__ __forceinline__ float fexp2(float x) {
#if __has_builtin(__builtin_amdgcn_exp2f)
    return __builtin_amdgcn_exp2f(x);
#else
    return exp2f(x);
#endif
}
__device__ __forceinline__ float frcp(float x) {
#if __has_builtin(__builtin_amdgcn_rcpf)
    return __builtin_amdgcn_rcpf(x);
#else
    return 1.0f / x;
#endif
}
// packed dual-fp32 FMA: a.x += b.x*c.x; a.y += b.y*c.y  (full-rate fp32 path)
__device__ __forceinline__ void pkfma(f32x2& a, f32x2 b, f32x2 c) {
    asm("v_pk_fma_f32 %0, %1, %2, %0" : "+v"(a) : "v"(b), "v"(c));
}
__device__ __forceinline__ f32x2 lo2(f32x4 v) { return __builtin_shufflevector(v, v, 0, 1); }
__device__ __forceinline__ f32x2 hi2(f32x4 v) { return __builtin_shufflevector(v, v, 2, 3); }

#define L2E  1.442695041f
#define L2E2 2.885390082f

// 1 wave = 1 batch row; lane = gate row g in [0,64); 2048 waves = 8 waves/CU.
// Pipelined: iteration k runs layer0@t=k+1 and layer1@t=k as two INDEPENDENT
// chains (both consume the same h0[t=k+1] broadcast). h broadcasts go through
// per-wave LDS lines (ds_write + 4x ds_read_b128) instead of 16 readlanes;
// per-wave LDS ops execute in order, so no barrier is needed.
__global__ __launch_bounds__(256, 2) void lstm2_kernel(
    const float* __restrict__ x,     // [B,T,1]
    const float* __restrict__ h0in,  // [2,B,16]
    const float* __restrict__ c0in,  // [2,B,16]
    const float* __restrict__ Wih0,  // [64,1]
    const float* __restrict__ Whh0,  // [64,16]
    const float* __restrict__ bih0,  // [64]
    const float* __restrict__ bhh0,  // [64]
    const float* __restrict__ Wih1,  // [64,16]
    const float* __restrict__ Whh1,  // [64,16]
    const float* __restrict__ bih1,  // [64]
    const float* __restrict__ bhh1,  // [64]
    float* __restrict__ out)         // [B*T*16] ++ hN[2,B,16] ++ cN[2,B,16]
{
    const int lane = threadIdx.x & 63;
    const int wid  = threadIdx.x >> 6;
    const int b    = blockIdx.x * 4 + wid;
    const int j    = lane & 15;

    // per-wave broadcast lines: [wave][layer][64 floats] (group-replicated)
    __shared__ __align__(16) float lds[4][2][64];
    float* l0 = lds[wid][0];
    float* l1 = lds[wid][1];
    const f32x4* r0 = (const f32x4*)(l0 + (lane & 48));  // own group's quarter
    const f32x4* r1 = (const f32x4*)(l1 + (lane & 48));

    // per-lane weight rows as packed pairs (pair r = elements 2r, 2r+1)
    f32x2 w0p[8], wi1p[8], w1p[8];
    {
        const f32x4* p0 = (const f32x4*)Whh0 + lane * 4;
        const f32x4* p1 = (const f32x4*)Wih1 + lane * 4;
        const f32x4* p2 = (const f32x4*)Whh1 + lane * 4;
#pragma unroll
        for (int r = 0; r < 4; ++r) {
            f32x4 a = p0[r], c = p1[r], d = p2[r];
            w0p[2*r] = lo2(a);  w0p[2*r+1] = hi2(a);
            wi1p[2*r] = lo2(c); wi1p[2*r+1] = hi2(c);
            w1p[2*r] = lo2(d);  w1p[2*r+1] = hi2(d);
        }
    }
    const float wx    = Wih0[lane];
    const float bias0 = bih0[lane] + bhh0[lane];
    const float bias1 = bih1[lane] + bhh1[lane];

    // state, replicated across all 4 lane-groups (every lane holds unit j)
    float h0v = h0in[0 * BB * HH + b * HH + j];
    float c0  = c0in[0 * BB * HH + b * HH + j];
    float h1v = h0in[1 * BB * HH + b * HH + j];
    float c1  = c0in[1 * BB * HH + b * HH + j];

    // initial broadcasts
    l0[lane] = h0v;
    l1[lane] = h1v;
    __builtin_amdgcn_sched_barrier(0);
    f32x4 hb0[4], hb1[4];
#pragma unroll
    for (int r = 0; r < 4; ++r) { hb0[r] = r0[r]; hb1[r] = r1[r]; }

    // activation selector: rows 0-31 (i,f) sigmoid, 32-47 (g) tanh, 48-63 (o) sigmoid
    const bool is_tanh = ((lane >> 4) == 2);
    const float Aa = is_tanh ? 2.0f  : 1.0f;
    const float Bb = is_tanh ? -L2E2 : -L2E;
    const float Cc = is_tanh ? -1.0f : 0.0f;
    const int ai = j * 4, af = ai + 64, ag = ai + 128, ao = ai + 192;
    const int phase = lane >> 4;
    float hist = 0.0f;

    const float* xp = x + (size_t)b * TT;
    float*       po = out + (size_t)b * TT * HH;

    // ---- prologue: layer 0 @ t=0 ----
    {
        float xt = xp[0];
        f32x2 a = { fmaf(xt, wx, bias0), 0.0f };   // .x = even-k chain, .y = odd-k chain
#pragma unroll
        for (int r = 0; r < 4; ++r) {
            pkfma(a, w0p[2*r],   lo2(hb0[r]));
            pkfma(a, w0p[2*r+1], hi2(hb0[r]));
        }
        float acc = a.x + a.y;
        float act = fmaf(Aa, frcp(1.0f + fexp2(Bb * acc)), Cc);
        float i_ = bperm(ai, act), f_ = bperm(af, act), g_ = bperm(ag, act), o_ = bperm(ao, act);
        c0  = fmaf(f_, c0, i_ * g_);
        h0v = o_ * fmaf(2.0f, frcp(1.0f + fexp2(-L2E2 * c0)), -1.0f);
        l0[lane] = h0v;
        __builtin_amdgcn_sched_barrier(0);
#pragma unroll
        for (int r = 0; r < 4; ++r) hb0[r] = r0[r];
    }

    // x staging, double-buffered one 64-block ahead
    int xnext = __float_as_int(xp[1 + lane]);
    int xcur  = 0;

#pragma unroll 4
    for (int k = 0; k < TT - 1; ++k) {
        if ((k & 63) == 0) {
            xcur = xnext;
            int idx = k + 65 + lane; if (idx > TT - 1) idx = TT - 1;
            xnext = __float_as_int(xp[idx]);
        }
        float xt = __int_as_float(__builtin_amdgcn_readlane(xcur, k & 63));

        // ---- chain A: layer 0 @ t=k+1; chain B: layer 1 @ t=k (independent) ----
        f32x2 a  = { fmaf(xt, wx, bias0), 0.0f };
        f32x2 bb = { bias1, 0.0f };
#pragma unroll
        for (int r = 0; r < 4; ++r) {
            f32x2 hlo = lo2(hb0[r]), hhi = hi2(hb0[r]);
            pkfma(a,  w0p[2*r],    hlo);
            pkfma(a,  w0p[2*r+1],  hhi);
            pkfma(bb, wi1p[2*r],   hlo);
            pkfma(bb, wi1p[2*r+1], hhi);
        }
#pragma unroll
        for (int r = 0; r < 4; ++r) {
            pkfma(bb, w1p[2*r],   lo2(hb1[r]));
            pkfma(bb, w1p[2*r+1], hi2(hb1[r]));
        }
        float acc0 = a.x + a.y;
        float acc1 = bb.x + bb.y;
        float act0 = fmaf(Aa, frcp(1.0f + fexp2(Bb * acc0)), Cc);
        float act1 = fmaf(Aa, frcp(1.0f + fexp2(Bb * acc1)), Cc);

        float i0 = bperm(ai, act0), f0 = bperm(af, act0), g0 = bperm(ag, act0), o0 = bperm(ao, act0);
        float i1 = bperm(ai, act1), f1 = bperm(af, act1), g1 = bperm(ag, act1), o1 = bperm(ao, act1);

        c0  = fmaf(f0, c0, i0 * g0);
        h0v = o0 * fmaf(2.0f, frcp(1.0f + fexp2(-L2E2 * c0)), -1.0f);
        c1  = fmaf(f1, c1, i1 * g1);
        h1v = o1 * fmaf(2.0f, frcp(1.0f + fexp2(-L2E2 * c1)), -1.0f);

        // refresh broadcasts via LDS (in-order per-wave DS => no barrier needed)
        l0[lane] = h0v;
        l1[lane] = h1v;
        __builtin_amdgcn_sched_barrier(0);
#pragma unroll
        for (int r = 0; r < 4; ++r) { hb0[r] = r0[r]; hb1[r] = r1[r]; }

        // out row k = h1 after step k; batch 4 rows per coalesced store
        hist = (phase == (k & 3)) ? h1v : hist;
        if ((k & 3) == 3) po[(size_t)(k - 3) * HH + lane] = hist;
    }

    // ---- epilogue: layer 1 @ t=TT-1 (consumes hb0 = bcast(h0_T)) ----
    {
        f32x2 bb = { bias1, 0.0f };
#pragma unroll
        for (int r = 0; r < 4; ++r) {
            pkfma(bb, wi1p[2*r],   lo2(hb0[r]));
            pkfma(bb, wi1p[2*r+1], hi2(hb0[r]));
        }
#pragma unroll
        for (int r = 0; r < 4; ++r) {
            pkfma(bb, w1p[2*r],   lo2(hb1[r]));
            pkfma(bb, w1p[2*r+1], hi2(hb1[r]));
        }
        float acc1 = bb.x + bb.y;
        float act1 = fmaf(Aa, frcp(1.0f + fexp2(Bb * acc1)), Cc);
        float i1 = bperm(ai, act1), f1 = bperm(af, act1), g1 = bperm(ag, act1), o1 = bperm(ao, act1);
        c1  = fmaf(f1, c1, i1 * g1);
        h1v = o1 * fmaf(2.0f, frcp(1.0f + fexp2(-L2E2 * c1)), -1.0f);
        hist = (phase == 3) ? h1v : hist;
        po[(size_t)(TT - 4) * HH + lane] = hist;  // rows 2044..2047
    }

    // final states: hN = [h_l0, h_l1], cN likewise (state replicated; group 0 writes)
    if (lane < 16) {
        const size_t offH = (size_t)BB * TT * HH;
        const size_t offC = offH + (size_t)2 * BB * HH;
        out[offH + 0 * BB * HH + b * HH + lane] = h0v;
        out[offH + 1 * BB * HH + b * HH + lane] = h1v;
        out[offC + 0 * BB * HH + b * HH + lane] = c0;
        out[offC + 1 * BB * HH + b * HH + lane] = c1;
    }
}

extern "C" void kernel_launch(void* const* d_in, const int* in_sizes, int n_in,
                              void* d_out, int out_size, void* d_ws, size_t ws_size,
                              hipStream_t stream) {
    const float* x    = (const float*)d_in[0];
    const float* h0   = (const float*)d_in[1];
    const float* c0   = (const float*)d_in[2];
    const float* Wih0 = (const float*)d_in[3];
    const float* Whh0 = (const float*)d_in[4];
    const float* bih0 = (const float*)d_in[5];
    const float* bhh0 = (const float*)d_in[6];
    const float* Wih1 = (const float*)d_in[7];
    const float* Whh1 = (const float*)d_in[8];
    const float* bih1 = (const float*)d_in[9];
    const float* bhh1 = (const float*)d_in[10];
    float* out = (float*)d_out;

    dim3 grid(BB / 4);   // 512 blocks x 4 waves = 2048 waves, one per batch row
    dim3 block(256);
    lstm2_kernel<<<grid, block, 0, stream>>>(x, h0, c0, Wih0, Whh0, bih0, bhh0,
                                             Wih1, Whh1, bih1, bhh1, out);
}